// Round 1
// 836.470 us; speedup vs baseline: 1.0809x; 1.0809x over previous
//
#include <hip/hip_runtime.h>

#define BB 8
#define TT 2048
#define CC 1024
#define FF 4096
#define MM (BB*TT)   // 16384

typedef unsigned short u16;
typedef __bf16 bf16x8 __attribute__((ext_vector_type(8)));
typedef float f32x4 __attribute__((ext_vector_type(4)));

__device__ __forceinline__ u16 f2bf(float f) {
  unsigned int u = __float_as_uint(f);
  u += 0x7fffu + ((u >> 16) & 1u);     // RNE to bf16
  return (u16)(u >> 16);
}
__device__ __forceinline__ float bf2f(u16 h) {
  unsigned int u = ((unsigned int)h) << 16;
  return __uint_as_float(u);
}
__device__ __forceinline__ float sigm(float x) { return 1.f / (1.f + __expf(-x)); }

__device__ __forceinline__ void async16(const void* g, void* l) {
  __builtin_amdgcn_global_load_lds(
      (const __attribute__((address_space(1))) unsigned int*)g,
      (__attribute__((address_space(3))) unsigned int*)l, 16, 0, 0);
}

// ---------------------------------------------------------------------------
// NT GEMM: C[m,n] = sum_k A[m,k]*W[n,k], A [M,K] bf16 row-major, W [N,K] bf16.
//
// 256x256 tile, BK=64, 512 thr (8 waves, 2Mx4N; each wave owns 128x64 = 8x4
// fragments of 16x16x32 MFMA). 8-phase-per-2-K-tiles schedule (T2+T3+T4+T5):
//   - double-buffered 2x(32KB A + 32KB B) LDS, global_load_lds(16B) staging
//   - global-source chunk XOR swizzle (chunk ^= row&7) + swizzled ds_read
//     -> 2-way (free) LDS banks, linear LDS dest (both-sides-or-neither)
//   - per K-tile: 4 phases {ds_read subtile || stage prefetch -> s_barrier ->
//     lgkmcnt(0)+sched_barrier -> setprio(1) 16xMFMA setprio(0) -> s_barrier}
//     quadrant order A0B0 / A1B0 / A0B1 / A1B1 (each frag read once/K-tile)
//   - counted s_waitcnt vmcnt(4) ONCE per K-tile (phase-2/3 stages stay in
//     flight across the barrier); drain vmcnt(0) only on the last two tiles.
// Staging region schedule (tile t's phases, all after the region's last
// reader passed lgkmcnt(0)+barrier):
//   Ph0: A(t+2) r0,r2 (read prev Ph3) + B(t+1) r2,r3 (buf nxt, dead)
//   Ph2: A(t+2) r1,r3 (read Ph1)
//   Ph3: B(t+2) r0,r1 (B fully read after Ph2)
// MODE 0: Cf[idx] = v (f32).
// MODE 2: Cb[idx] = bf16(relu(v)^2).
// MODE 3: Cb[idx] = bf16(v).
// MODE 4: Cf[idx] += sigm(R[idx]) * v (f32 in-place; R bf16).
// ---------------------------------------------------------------------------
#define GROUP_M 16

#define DSR(d, a) asm volatile("ds_read_b128 %0, %1" : "=v"(d) : "v"(a))
#define MFMA16(A_, B_, C_) \
  (C_) = __builtin_amdgcn_mfma_f32_16x16x32_bf16( \
      __builtin_bit_cast(bf16x8, (A_)), __builtin_bit_cast(bf16x8, (B_)), (C_), 0, 0, 0)

#define PH_MID() do { \
  __builtin_amdgcn_s_barrier(); \
  asm volatile("s_waitcnt lgkmcnt(0)"); \
  __builtin_amdgcn_sched_barrier(0); \
  __builtin_amdgcn_s_setprio(1); } while (0)

#define PH_END() do { \
  __builtin_amdgcn_s_setprio(0); \
  __builtin_amdgcn_sched_barrier(0); \
  __builtin_amdgcn_s_barrier(); } while (0)

template<int MODE>
__global__ __launch_bounds__(512, 2) void gemm_bt(
    const u16* __restrict__ A, const u16* __restrict__ W,
    float* __restrict__ Cf, u16* __restrict__ Cb,
    const u16* __restrict__ R, int N, int K)
{
  __shared__ __align__(16) u16 ldsA[2][256 * 64];   // 64 KB
  __shared__ __align__(16) u16 ldsB[2][256 * 64];   // 64 KB

  const int tid  = threadIdx.x;
  const int wave = tid >> 6;
  const int lane = tid & 63;
  const int wmi  = wave >> 2;          // 0..1 : wave M row (128 rows each)
  const int wni  = wave & 3;           // 0..3 : wave N col (64 cols each)
  const int lm   = lane & 15;
  const int lq   = lane >> 4;

  // tile swizzle (grid.x = M/256 = 64, divisible by GROUP_M; grid.y = N/256)
  const int bid  = blockIdx.x + blockIdx.y * gridDim.x;
  const int gsz  = GROUP_M * gridDim.y;
  const int gid  = bid / gsz;
  const int rem  = bid - gid * gsz;
  const int bm   = (gid * GROUP_M + (rem % GROUP_M)) * 256;
  const int bn   = (rem / GROUP_M) * 256;

  const int NT = K >> 6;               // K-tiles of 64

  // staging source: round q covers rows [q*64, q*64+64), wave-interleaved.
  // chunk pre-swizzle (involution chunk ^= row&7) so linear LDS dest +
  // swizzled ds_read line up.  row&7 == lane>>3 here.
  const int srow   = wave * 8 + (lane >> 3);
  const int schunk = (lane & 7) ^ (lane >> 3);
  const u16* gA = A + (size_t)(bm + srow) * K + schunk * 8;
  const u16* gB = W + (size_t)(bn + srow) * K + schunk * 8;
  const size_t rowK = (size_t)64 * K;

  auto stA = [&](int buf, int q, int t2) {
    async16(gA + (size_t)t2 * 64 + (size_t)q * rowK,
            &ldsA[buf][(q * 64 + wave * 8) * 64]);
  };
  auto stB = [&](int buf, int q, int t2) {
    async16(gB + (size_t)t2 * 64 + (size_t)q * rowK,
            &ldsB[buf][(q * 64 + wave * 8) * 64]);
  };

  // LDS byte addresses for asm ds_read (AS3 offset)
  const unsigned lAbase =
      (unsigned)(size_t)(const __attribute__((address_space(3))) u16*)&ldsA[0][0];
  const unsigned lBbase =
      (unsigned)(size_t)(const __attribute__((address_space(3))) u16*)&ldsB[0][0];
  // fragment read offsets: row = (wrow + mi*16 + lm), k-chunk (lq + 4*kh),
  // byte = row*128 + ((lq+4*kh) ^ (row&7))*16 ; row&7 == lm&7.
  const unsigned aof0 = (unsigned)((wmi * 128 + lm) * 128 + (((lq    ) ^ (lm & 7)) * 16));
  const unsigned aof1 = (unsigned)((wmi * 128 + lm) * 128 + (((lq + 4) ^ (lm & 7)) * 16));
  const unsigned bof0 = (unsigned)((wni *  64 + lm) * 128 + (((lq    ) ^ (lm & 7)) * 16));
  const unsigned bof1 = (unsigned)((wni *  64 + lm) * 128 + (((lq + 4) ^ (lm & 7)) * 16));

  f32x4 acc[8][4] = {};
  f32x4 a0[4][2], a1[4][2], b[2][2];   // frag banks (static-indexed only)

  // ---------------- prologue ----------------
  // tile0: A r0..r3, B r0..r3 ; tile1: A r0,r2,r1,r3 ; tile1: B r0,r1
  stA(0, 0, 0); stA(0, 1, 0); stA(0, 2, 0); stA(0, 3, 0);
  stB(0, 0, 0); stB(0, 1, 0); stB(0, 2, 0); stB(0, 3, 0);
  stA(1, 0, 1); stA(1, 2, 1); stA(1, 1, 1); stA(1, 3, 1);
  stB(1, 0, 1); stB(1, 1, 1);
  // need first 10 landed (tile0 all + A(1) r0,r2); last 4 stay in flight
  asm volatile("s_waitcnt vmcnt(4)");
  __builtin_amdgcn_s_barrier();
#pragma unroll
  for (int mi = 0; mi < 4; ++mi) {
    DSR(a0[mi][0], lAbase + aof0 + mi * 2048);
    DSR(a0[mi][1], lAbase + aof1 + mi * 2048);
  }

  for (int t = 0; t < NT; ++t) {
    const int cur = t & 1, nxt = cur ^ 1;
    const unsigned cA = lAbase + cur * 32768;
    const unsigned cB = lBbase + cur * 32768;
    const unsigned nA = lAbase + nxt * 32768;
    const bool s2 = (t + 2 < NT);
    const bool s1 = (t + 1 < NT);

    // ---- phase 0: read B0 (ni 0,1); stage A(t+2) r0,r2 + B(t+1) r2,r3
#pragma unroll
    for (int ni = 0; ni < 2; ++ni) {
      DSR(b[ni][0], cB + bof0 + ni * 2048);
      DSR(b[ni][1], cB + bof1 + ni * 2048);
    }
    if (s2) { stA(cur, 0, t + 2); stA(cur, 2, t + 2); }
    if (s1) { stB(nxt, 2, t + 1); stB(nxt, 3, t + 1); }
    PH_MID();
#pragma unroll
    for (int mi = 0; mi < 4; ++mi)
#pragma unroll
      for (int ni = 0; ni < 2; ++ni) {
        MFMA16(a0[mi][0], b[ni][0], acc[mi][ni]);
        MFMA16(a0[mi][1], b[ni][1], acc[mi][ni]);
      }
    PH_END();

    // ---- phase 1: read A1 (mi 4..7); no staging
#pragma unroll
    for (int mi = 0; mi < 4; ++mi) {
      DSR(a1[mi][0], cA + aof0 + (4 + mi) * 2048);
      DSR(a1[mi][1], cA + aof1 + (4 + mi) * 2048);
    }
    PH_MID();
#pragma unroll
    for (int mi = 0; mi < 4; ++mi)
#pragma unroll
      for (int ni = 0; ni < 2; ++ni) {
        MFMA16(a1[mi][0], b[ni][0], acc[4 + mi][ni]);
        MFMA16(a1[mi][1], b[ni][1], acc[4 + mi][ni]);
      }
    PH_END();

    // ---- phase 2: read B1 (ni 2,3); stage A(t+2) r1,r3
#pragma unroll
    for (int ni = 0; ni < 2; ++ni) {
      DSR(b[ni][0], cB + bof0 + (2 + ni) * 2048);
      DSR(b[ni][1], cB + bof1 + (2 + ni) * 2048);
    }
    if (s2) { stA(cur, 1, t + 2); stA(cur, 3, t + 2); }
    PH_MID();
#pragma unroll
    for (int mi = 0; mi < 4; ++mi)
#pragma unroll
      for (int ni = 0; ni < 2; ++ni) {
        MFMA16(a0[mi][0], b[ni][0], acc[mi][2 + ni]);
        MFMA16(a0[mi][1], b[ni][1], acc[mi][2 + ni]);
      }
    PH_END();

    // ---- phase 3: read A0(t+1) from nxt buf; stage B(t+2) r0,r1
    if (s1) {
#pragma unroll
      for (int mi = 0; mi < 4; ++mi) {
        DSR(a0[mi][0], nA + aof0 + mi * 2048);
        DSR(a0[mi][1], nA + aof1 + mi * 2048);
      }
    }
    if (s2) { stB(cur, 0, t + 2); stB(cur, 1, t + 2); }
    PH_MID();
#pragma unroll
    for (int mi = 0; mi < 4; ++mi)
#pragma unroll
      for (int ni = 0; ni < 2; ++ni) {
        MFMA16(a1[mi][0], b[ni][0], acc[4 + mi][2 + ni]);
        MFMA16(a1[mi][1], b[ni][1], acc[4 + mi][2 + ni]);
      }
    __builtin_amdgcn_s_setprio(0);
    __builtin_amdgcn_sched_barrier(0);
    // counted wait: the 4 loads from phases 2-3 stay in flight (never 0
    // in the main loop); drain only when no further staging exists.
    if (t < NT - 2) asm volatile("s_waitcnt vmcnt(4)");
    else            asm volatile("s_waitcnt vmcnt(0)");
    __builtin_amdgcn_s_barrier();
  }

  // epilogue. C/D layout (verified m89/m91): col = lane&15, row = (lane>>4)*4 + reg
  const int row0 = bm + wmi * 128 + lq * 4;
  const int col0 = bn + wni * 64 + lm;
#pragma unroll
  for (int mi = 0; mi < 8; ++mi)
#pragma unroll
    for (int ni = 0; ni < 4; ++ni) {
      size_t base = (size_t)(row0 + mi * 16) * N + (col0 + ni * 16);
#pragma unroll
      for (int r2 = 0; r2 < 4; ++r2) {
        size_t idx = base + (size_t)r2 * N;
        float v = acc[mi][ni][r2];
        if (MODE == 0) Cf[idx] = v;
        if (MODE == 2) { float rl = v > 0.f ? v : 0.f; Cb[idx] = f2bf(rl * rl); }
        if (MODE == 3) Cb[idx] = f2bf(v);
        if (MODE == 4) Cf[idx] += sigm(bf2f(R[idx])) * v;
      }
    }
}

// ---------------------------------------------------------------------------
// LayerNorm both rows t and t-1, time-shift mix, bf16 cast.
// One block per row (b,t). ov/oxb may be null (phase-2 use).
// oxb (raw x cast) is written at pitch 2*CC (the A' interleaved buffer).
// ---------------------------------------------------------------------------
__global__ __launch_bounds__(256) void prep_mix(
    const float* __restrict__ x,
    const float* __restrict__ lnw, const float* __restrict__ lnb,
    const float* __restrict__ mk, const float* __restrict__ mv, const float* __restrict__ mr,
    u16* __restrict__ ok, u16* __restrict__ ov, u16* __restrict__ orr,
    u16* __restrict__ oxb)
{
  const int m = blockIdx.x;
  const int t = m & (TT - 1);
  const int tid = threadIdx.x;
  const int wave = tid >> 6, lane = tid & 63;
  const bool hasp = (t != 0);

  const float4 xc4 = ((const float4*)(x + (size_t)m * CC))[tid];
  float4 xp4 = make_float4(0.f, 0.f, 0.f, 0.f);
  if (hasp) xp4 = ((const float4*)(x + (size_t)(m - 1) * CC))[tid];

  float s0 = xc4.x + xc4.y + xc4.z + xc4.w;
  float s1 = xc4.x*xc4.x + xc4.y*xc4.y + xc4.z*xc4.z + xc4.w*xc4.w;
  float s2 = xp4.x + xp4.y + xp4.z + xp4.w;
  float s3 = xp4.x*xp4.x + xp4.y*xp4.y + xp4.z*xp4.z + xp4.w*xp4.w;
#pragma unroll
  for (int off2 = 32; off2 > 0; off2 >>= 1) {
    s0 += __shfl_xor(s0, off2);
    s1 += __shfl_xor(s1, off2);
    s2 += __shfl_xor(s2, off2);
    s3 += __shfl_xor(s3, off2);
  }
  __shared__ float red[4][4];
  if (lane == 0) { red[0][wave] = s0; red[1][wave] = s1; red[2][wave] = s2; red[3][wave] = s3; }
  __syncthreads();
  const float S0 = red[0][0] + red[0][1] + red[0][2] + red[0][3];
  const float S1 = red[1][0] + red[1][1] + red[1][2] + red[1][3];
  const float S2 = red[2][0] + red[2][1] + red[2][2] + red[2][3];
  const float S3 = red[3][0] + red[3][1] + red[3][2] + red[3][3];
  const float inv = 1.f / (float)CC;
  const float muc = S0 * inv, varc = S1 * inv - muc * muc, rsc = rsqrtf(varc + 1e-5f);
  const float mup = S2 * inv, varp = S3 * inv - mup * mup, rsp = rsqrtf(varp + 1e-5f);

  const float xc[4] = {xc4.x, xc4.y, xc4.z, xc4.w};
  const float xp[4] = {xp4.x, xp4.y, xp4.z, xp4.w};
  const float4 lw4 = ((const float4*)lnw)[tid];
  const float4 lb4 = ((const float4*)lnb)[tid];
  const float lw[4] = {lw4.x, lw4.y, lw4.z, lw4.w};
  const float lb[4] = {lb4.x, lb4.y, lb4.z, lb4.w};
  const float4 mk4 = ((const float4*)mk)[tid];
  const float mka[4] = {mk4.x, mk4.y, mk4.z, mk4.w};
  const float4 mr4 = ((const float4*)mr)[tid];
  const float mra[4] = {mr4.x, mr4.y, mr4.z, mr4.w};
  float mva[4] = {0.f, 0.f, 0.f, 0.f};
  if (ov) {
    const float4 mv4 = ((const float4*)mv)[tid];
    mva[0] = mv4.x; mva[1] = mv4.y; mva[2] = mv4.z; mva[3] = mv4.w;
  }

  ushort4 wk2, wv2, wr2, wb2;
  u16* pk = (u16*)&wk2; u16* pv = (u16*)&wv2; u16* pr = (u16*)&wr2; u16* pb = (u16*)&wb2;
#pragma unroll
  for (int j = 0; j < 4; ++j) {
    float h  = (xc[j] - muc) * rsc * lw[j] + lb[j];
    float hh = hasp ? (xp[j] - mup) * rsp * lw[j] + lb[j] : 0.f;
    pk[j] = f2bf(h * mka[j] + hh * (1.f - mka[j]));
    pv[j] = f2bf(h * mva[j] + hh * (1.f - mva[j]));
    pr[j] = f2bf(h * mra[j] + hh * (1.f - mra[j]));
    pb[j] = f2bf(xc[j]);
  }
  ((ushort4*)(ok + (size_t)m * CC))[tid] = wk2;
  if (ov)  ((ushort4*)(ov  + (size_t)m * CC))[tid] = wv2;
  ((ushort4*)(orr + (size_t)m * CC))[tid] = wr2;
  if (oxb) ((ushort4*)(oxb + (size_t)m * (2 * CC)))[tid] = wb2;   // A' xb half
}

// ---------------------------------------------------------------------------
// WKV blocked 3-phase parallel scan. Output goes to the rwkv half of the
// interleaved A' buffer: out pitch = 2*CC.
// ---------------------------------------------------------------------------
#define WKV_CPB 32
#define WKV_NCH 32
#define WKV_L   (TT / WKV_NCH)   // 64

__global__ __launch_bounds__(1024) void wkv_scan(
    const u16* __restrict__ k, const u16* __restrict__ v, const u16* __restrict__ r,
    const float* __restrict__ decay, const float* __restrict__ first,
    u16* __restrict__ out)   // points at A' + CC (rwkv half), pitch 2*CC
{
  const int b  = blockIdx.x >> 5;
  const int c0 = (blockIdx.x & 31) * WKV_CPB;
  const int tid = threadIdx.x;
  const int cl = tid & 31;
  const int j  = tid >> 5;
  const int c  = c0 + cl;

  const float w   = -__expf(decay[c]);
  const float lam = __expf(w);
  const float eu  = __expf(first[c]);

  const size_t base  = (size_t)b * TT * CC + (size_t)j * WKV_L * CC + c;
  size_t obase = ((size_t)b * TT + (size_t)j * WKV_L) * (2 * CC) + c;

  // phase 1: local scan (state only)
  float a = 0.f, bb = 0.f;
  size_t idx = base;
  for (int i = 0; i < WKV_L; ++i, idx += CC) {
    const float kt = bf2f(k[idx]), vt = bf2f(v[idx]);
    const float ek = __expf(kt);
    a  = fmaf(lam, a, ek * vt);
    bb = fmaf(lam, bb, ek);
  }

  // phase 2: exclusive carry scan over chunks
  __shared__ float sA[WKV_NCH][WKV_CPB];
  __shared__ float sB[WKV_NCH][WKV_CPB];
  sA[j][cl] = a; sB[j][cl] = bb;
  __syncthreads();
  if (tid < WKV_CPB) {
    float ca = 0.f, cb = 0.f;
    const float cw   = -__expf(decay[c0 + tid]);
    const float cLam = __expf(cw * (float)WKV_L);
#pragma unroll
    for (int q = 0; q < WKV_NCH; ++q) {
      const float ta = sA[q][tid], tb = sB[q][tid];
      sA[q][tid] = ca; sB[q][tid] = cb;
      ca = fmaf(cLam, ca, ta);
      cb = fmaf(cLam, cb, tb);
    }
  }
  __syncthreads();
  a = sA[j][cl]; bb = sB[j][cl];

  // phase 3: replay with carry-in, emit sigmoid(r)*y into A' rwkv half
  idx = base;
  for (int i = 0; i < WKV_L; ++i, idx += CC, obase += 2 * CC) {
    const float kt = bf2f(k[idx]), vt = bf2f(v[idx]), rt = bf2f(r[idx]);
    const float ek = __expf(kt);
    const float e2 = eu * ek;
    const float y  = (a + e2 * vt) / (bb + e2);
    out[obase] = f2bf(sigm(rt) * y);
    a  = fmaf(lam, a, ek * vt);
    bb = fmaf(lam, bb, ek);
  }
}

// ---------------------------------------------------------------------------
// Weight f32 -> bf16 conversion. Segments 3 (Wo) and 4 (Wsh) are interleaved
// into W' = [Wsh | Wo] rows of pitch 2048 for the merged short+Wo GEMM.
// ---------------------------------------------------------------------------
struct ConvArgs { const float* src[8]; int end[8]; int dstoff[8]; };

__global__ __launch_bounds__(256) void conv_w(ConvArgs args, u16* __restrict__ dst)
{
  const int i = (blockIdx.x * 256 + threadIdx.x) * 4;
  int seg = 0;
  const float* sp = args.src[0];
  int base = 0;
#pragma unroll
  for (int s = 1; s < 8; ++s) {
    if (i >= args.end[s - 1]) { seg = s; sp = args.src[s]; base = args.end[s - 1]; }
  }
  const int l = i - base;
  const float4 vv = *(const float4*)(sp + l);
  int dsti;
  if (seg == 3)      { int row = l >> 10, col = l & 1023; dsti = args.dstoff[3] + row * 2048 + 1024 + col; }
  else if (seg == 4) { int row = l >> 10, col = l & 1023; dsti = args.dstoff[4] + row * 2048 + col; }
  else               dsti = args.dstoff[seg] + l;
  ushort4 d;
  d.x = f2bf(vv.x); d.y = f2bf(vv.y); d.z = f2bf(vv.z); d.w = f2bf(vv.w);
  *(ushort4*)(dst + dsti) = d;
}

extern "C" void kernel_launch(void* const* d_in, const int* in_sizes, int n_in,
                              void* d_out, int out_size, void* d_ws, size_t ws_size,
                              hipStream_t stream)
{
  const float* x    = (const float*)d_in[0];
  const float* ln1w = (const float*)d_in[1];
  const float* ln1b = (const float*)d_in[2];
  const float* ln2w = (const float*)d_in[3];
  const float* ln2b = (const float*)d_in[4];
  const float* tdec = (const float*)d_in[5];
  const float* tfir = (const float*)d_in[6];
  const float* amk  = (const float*)d_in[7];
  const float* amv  = (const float*)d_in[8];
  const float* amr  = (const float*)d_in[9];
  const float* Wk   = (const float*)d_in[10];
  const float* Wv   = (const float*)d_in[11];
  const float* Wr   = (const float*)d_in[12];
  const float* Wo   = (const float*)d_in[13];
  const float* fmk  = (const float*)d_in[14];
  const float* fmr  = (const float*)d_in[15];
  const float* WfK  = (const float*)d_in[16];
  const float* WfR  = (const float*)d_in[17];
  const float* WfV  = (const float*)d_in[18];
  const float* Wsh  = (const float*)d_in[19];
  float* out = (float*)d_out;
  char* ws = (char*)d_ws;

  // workspace: 28 MB bf16 weights + six 32 MB regions = 230,686,720 B total.
  u16* wW = (u16*)(ws);
  u16* U0 = (u16*)(ws + 29360128);
  u16* U1 = (u16*)(ws + 62914560);
  u16* U2 = (u16*)(ws + 96468992);
  u16* U3 = (u16*)(ws + 130023424);
  u16* U4 = (u16*)(ws + 163577856);   // A' = U4+U5, 64 MB contiguous

  // liveness-based aliases:
  u16* xk   = U0;          // prep1
  u16* xv   = U1;
  u16* xr   = U2;
  u16* Ap   = U4;          // A' [M, 2C]: cols 0..C-1 = bf16(x), C..2C-1 = rwkv
  u16* kbuf = U3;          // k = xk*Wk   (U0 dead after)
  u16* vbuf = U0;          // v = xv*Wv   (U1 dead after)
  u16* rbuf = U1;          // r = xr*Wr   (U2 dead after)
  u16* gk   = U0;          // prep2       (U0 dead after wkv)
  u16* gr   = U1;
  u16* kkb  = U2;          // kk [M,F] bf16 = 128 MB, spans U2..U5 (all dead)
  u16* rffn = U0;          // r_ffn       (gk/U0 dead after kk GEMM)

  u16* bWk   = wW + 0;
  u16* bWv   = wW + 1048576;
  u16* bWr   = wW + 2097152;
  u16* bWsWo = wW + 3145728;   // W' [C, 2C] interleaved [Wsh | Wo]
  u16* bWfR  = wW + 5242880;
  u16* bWfK  = wW + 6291456;
  u16* bWfV  = wW + 10485760;

  ConvArgs ca;
  ca.src[0] = Wk;  ca.src[1] = Wv;  ca.src[2] = Wr;  ca.src[3] = Wo;
  ca.src[4] = Wsh; ca.src[5] = WfR; ca.src[6] = WfK; ca.src[7] = WfV;
  const int e = 1048576;
  ca.end[0] = e;     ca.end[1] = 2*e;  ca.end[2] = 3*e;  ca.end[3] = 4*e;
  ca.end[4] = 5*e;   ca.end[5] = 6*e;  ca.end[6] = 10*e; ca.end[7] = 14*e;
  ca.dstoff[0] = 0;     ca.dstoff[1] = e;    ca.dstoff[2] = 2*e;
  ca.dstoff[3] = 3*e;   ca.dstoff[4] = 3*e;  // both into W' (interleaved)
  ca.dstoff[5] = 5*e;   ca.dstoff[6] = 6*e;  ca.dstoff[7] = 10*e;

  conv_w<<<14336, 256, 0, stream>>>(ca, wW);
  prep_mix<<<MM, 256, 0, stream>>>(x, ln1w, ln1b, amk, amv, amr, xk, xv, xr, Ap);

  dim3 g8(MM / 256, CC / 256);
  gemm_bt<3><<<g8, 512, 0, stream>>>(xk, bWk, nullptr, kbuf, nullptr, CC, CC);
  gemm_bt<3><<<g8, 512, 0, stream>>>(xv, bWv, nullptr, vbuf, nullptr, CC, CC);
  gemm_bt<3><<<g8, 512, 0, stream>>>(xr, bWr, nullptr, rbuf, nullptr, CC, CC);

  wkv_scan<<<BB * (CC / WKV_CPB), 1024, 0, stream>>>(kbuf, vbuf, rbuf, tdec, tfir, Ap + CC);

  // out = [xb | rwkv] * [Wsh | Wo]^T   (single K=2048 GEMM)
  gemm_bt<0><<<g8, 512, 0, stream>>>(Ap, bWsWo, out, nullptr, nullptr, CC, 2 * CC);

  prep_mix<<<MM, 256, 0, stream>>>(out, ln2w, ln2b, fmk, nullptr, fmr, gk, nullptr, gr, nullptr);

  dim3 gF(MM / 256, FF / 256);
  gemm_bt<2><<<gF, 512, 0, stream>>>(gk, bWfK, nullptr, kkb, nullptr, FF, CC);  // kk = relu(gk*WfK)^2
  gemm_bt<3><<<g8, 512, 0, stream>>>(gr, bWfR, nullptr, rffn, nullptr, CC, CC);
  // out += sigm(rffn) * (kk * WfV)   (fused final_add)
  gemm_bt<4><<<g8, 512, 0, stream>>>(kkb, bWfV, out, nullptr, rffn, CC, FF);
}